// Round 10
// baseline (922.527 us; speedup 1.0000x reference)
//
#include <hip/hip_runtime.h>
#include <math.h>

#define N_NODES 50000
#define N_EDGES 800000
#define HID 128
#define OUTC 64
#define NLAYERS 8

#define SCAN_B 64
#define SCAN_T 256
#define SCAN_C 4   // 64*256*4 = 65536 >= 50000

// ---------------- bf16 helpers (manual, RNE) ----------------

__device__ __forceinline__ float bfloat_lo(unsigned int u) {
    return __int_as_float((int)(u << 16));
}
__device__ __forceinline__ float bfloat_hi(unsigned int u) {
    return __int_as_float((int)(u & 0xFFFF0000u));
}
__device__ __forceinline__ unsigned int f2bf(float f) {
    unsigned int u = (unsigned int)__float_as_int(f);
    return (u + 0x7FFFu + ((u >> 16) & 1u)) >> 16;
}
__device__ __forceinline__ unsigned int pack2bf(float a, float b) {
    return f2bf(a) | (f2bf(b) << 16);
}

// ---------------- CSR build ----------------

__global__ void k_zero(int* __restrict__ p, int n) {
    int i = blockIdx.x * blockDim.x + threadIdx.x;
    if (i < n) p[i] = 0;
}

__global__ void k_count(const int* __restrict__ dst, int* __restrict__ deg, int E) {
    int e = blockIdx.x * blockDim.x + threadIdx.x;
    if (e < E) atomicAdd(&deg[dst[e]], 1);
}

__global__ __launch_bounds__(SCAN_T) void k_scanA(const int* __restrict__ deg, int* __restrict__ bsum) {
    __shared__ int red[SCAN_T];
    const int t = threadIdx.x, b = blockIdx.x;
    const int g = b * SCAN_T + t;
    int lo = g * SCAN_C; if (lo > N_NODES) lo = N_NODES;
    int hi = lo + SCAN_C; if (hi > N_NODES) hi = N_NODES;
    int s = 0;
    for (int i = lo; i < hi; i++) s += deg[i];
    red[t] = s;
    __syncthreads();
    for (int d = SCAN_T / 2; d > 0; d >>= 1) {
        if (t < d) red[t] += red[t + d];
        __syncthreads();
    }
    if (t == 0) bsum[b] = red[0];
}

__global__ __launch_bounds__(SCAN_T) void k_scanB(int* __restrict__ cur, int* __restrict__ off,
                                                  const int* __restrict__ bsum) {
    __shared__ int pre[SCAN_T];
    __shared__ int baseSh;
    const int t = threadIdx.x, b = blockIdx.x;
    const int g = b * SCAN_T + t;
    int lo = g * SCAN_C; if (lo > N_NODES) lo = N_NODES;
    int hi = lo + SCAN_C; if (hi > N_NODES) hi = N_NODES;
    int s = 0;
    for (int i = lo; i < hi; i++) s += cur[i];
    pre[t] = s;
    if (t == 0) {
        int acc = 0;
        for (int j = 0; j < b; j++) acc += bsum[j];
        baseSh = acc;
    }
    __syncthreads();
    for (int d = 1; d < SCAN_T; d <<= 1) {
        int v = (t >= d) ? pre[t - d] : 0;
        __syncthreads();
        pre[t] += v;
        __syncthreads();
    }
    int running = baseSh + pre[t] - s;
    for (int i = lo; i < hi; i++) {
        int d = cur[i];
        off[i] = running;
        cur[i] = running;
        running += d;
        if (i == N_NODES - 1) off[N_NODES] = running;
    }
}

__global__ void k_scatter(const int* __restrict__ src, const int* __restrict__ dst,
                          const float* __restrict__ w, int* __restrict__ cursor,
                          int2* __restrict__ ep, int E) {
    int e = blockIdx.x * blockDim.x + threadIdx.x;
    if (e < E) {
        int d = dst[e];
        int pos = atomicAdd(&cursor[d], 1);
        ep[pos] = make_int2(src[e], __float_as_int(w[e]));
    }
}

// ---------------- bf16 gather (128 ch): one edge per wave-instruction ----------------
// lane covers ch c=lane*2 -> one u32 load per edge (row = 64 u32, fully coalesced 256B)
// 8 independent row loads in flight per unroll step.
__device__ __forceinline__ void gatherB2(const int2* __restrict__ ep, int lo, int hi,
                                         const unsigned int* __restrict__ featsU, int lane,
                                         float& ax, float& ay)
{
    for (int base = lo; base < hi; base += 64) {
        const int cnt = min(hi - base, 64);
        int2 ev = make_int2(0, 0);
        if (lane < cnt) ev = ep[base + lane];
        int j = 0;
        for (; j + 8 <= cnt; j += 8) {
            int s0 = __shfl(ev.x, j + 0), s1 = __shfl(ev.x, j + 1);
            int s2 = __shfl(ev.x, j + 2), s3 = __shfl(ev.x, j + 3);
            int s4 = __shfl(ev.x, j + 4), s5 = __shfl(ev.x, j + 5);
            int s6 = __shfl(ev.x, j + 6), s7 = __shfl(ev.x, j + 7);
            float w0 = __int_as_float(__shfl(ev.y, j + 0));
            float w1 = __int_as_float(__shfl(ev.y, j + 1));
            float w2 = __int_as_float(__shfl(ev.y, j + 2));
            float w3 = __int_as_float(__shfl(ev.y, j + 3));
            float w4 = __int_as_float(__shfl(ev.y, j + 4));
            float w5 = __int_as_float(__shfl(ev.y, j + 5));
            float w6 = __int_as_float(__shfl(ev.y, j + 6));
            float w7 = __int_as_float(__shfl(ev.y, j + 7));
            unsigned int u0 = featsU[(size_t)s0 * 64 + lane];
            unsigned int u1 = featsU[(size_t)s1 * 64 + lane];
            unsigned int u2 = featsU[(size_t)s2 * 64 + lane];
            unsigned int u3 = featsU[(size_t)s3 * 64 + lane];
            unsigned int u4 = featsU[(size_t)s4 * 64 + lane];
            unsigned int u5 = featsU[(size_t)s5 * 64 + lane];
            unsigned int u6 = featsU[(size_t)s6 * 64 + lane];
            unsigned int u7 = featsU[(size_t)s7 * 64 + lane];
            ax = fmaf(w0, bfloat_lo(u0), ax); ay = fmaf(w0, bfloat_hi(u0), ay);
            ax = fmaf(w1, bfloat_lo(u1), ax); ay = fmaf(w1, bfloat_hi(u1), ay);
            ax = fmaf(w2, bfloat_lo(u2), ax); ay = fmaf(w2, bfloat_hi(u2), ay);
            ax = fmaf(w3, bfloat_lo(u3), ax); ay = fmaf(w3, bfloat_hi(u3), ay);
            ax = fmaf(w4, bfloat_lo(u4), ax); ay = fmaf(w4, bfloat_hi(u4), ay);
            ax = fmaf(w5, bfloat_lo(u5), ax); ay = fmaf(w5, bfloat_hi(u5), ay);
            ax = fmaf(w6, bfloat_lo(u6), ax); ay = fmaf(w6, bfloat_hi(u6), ay);
            ax = fmaf(w7, bfloat_lo(u7), ax); ay = fmaf(w7, bfloat_hi(u7), ay);
        }
        for (; j < cnt; j++) {
            int s = __shfl(ev.x, j);
            float w = __int_as_float(__shfl(ev.y, j));
            unsigned int u = featsU[(size_t)s * 64 + lane];
            ax = fmaf(w, bfloat_lo(u), ax); ay = fmaf(w, bfloat_hi(u), ay);
        }
    }
}

// ---------------- input spmm: h0 = relu(spmm(z bf16) + b_in) -> h bf16 AND x0 bf16 ----------------
__global__ __launch_bounds__(256) void k_spmm_in(
    const int* __restrict__ off, const int2* __restrict__ ep,
    const unsigned int* __restrict__ zU, const float* __restrict__ b_in,
    unsigned int* __restrict__ hU, unsigned int* __restrict__ x0U)
{
    const int wave = threadIdx.x >> 6;
    const int lane = threadIdx.x & 63;
    const int node = blockIdx.x * 4 + wave;
    if (node >= N_NODES) return;
    const int lo = off[node], hi = off[node + 1];

    float ax = 0.f, ay = 0.f;
    gatherB2(ep, lo, hi, zU, lane, ax, ay);
    const int c = lane * 2;
    float r0 = fmaxf(ax + b_in[c], 0.f);
    float r1 = fmaxf(ay + b_in[c + 1], 0.f);
    unsigned int pk = pack2bf(r0, r1);
    hU [(size_t)node * 64 + lane] = pk;
    x0U[(size_t)node * 64 + lane] = pk;
}

// ---------------- final spmm: out = spmm(y bf16, 64ch) + b_out (4 edges per load) ----------------
__global__ __launch_bounds__(256) void k_spmm_out(
    const int* __restrict__ off, const int2* __restrict__ ep,
    const uint2* __restrict__ yU2, const float* __restrict__ b_out,
    float* __restrict__ out)
{
    const int wave = threadIdx.x >> 6;
    const int lane = threadIdx.x & 63;
    const int node = blockIdx.x * 4 + wave;
    if (node >= N_NODES) return;
    const int q = lane >> 4;       // edge slot within quad
    const int s16 = lane & 15;     // ch group: ch = s16*4..+3

    float acc[4] = {0.f, 0.f, 0.f, 0.f};
    const int lo = off[node], hi = off[node + 1];
    for (int base = lo; base < hi; base += 64) {
        const int cnt = min(hi - base, 64);
        int2 ev = make_int2(0, 0);
        if (lane < cnt) ev = ep[base + lane];
        const int kmax = (cnt + 3) & ~3;
        int j = 0;
        for (; j + 8 <= kmax; j += 8) {
            int e0 = j + q, e1 = j + 4 + q;
            int s0 = __shfl(ev.x, e0), s1 = __shfl(ev.x, e1);
            float w0 = __int_as_float(__shfl(ev.y, e0));
            float w1 = __int_as_float(__shfl(ev.y, e1));
            uint2 u0 = yU2[(size_t)s0 * 16 + s16];
            uint2 u1 = yU2[(size_t)s1 * 16 + s16];
            acc[0] = fmaf(w0, bfloat_lo(u0.x), acc[0]);
            acc[1] = fmaf(w0, bfloat_hi(u0.x), acc[1]);
            acc[2] = fmaf(w0, bfloat_lo(u0.y), acc[2]);
            acc[3] = fmaf(w0, bfloat_hi(u0.y), acc[3]);
            acc[0] = fmaf(w1, bfloat_lo(u1.x), acc[0]);
            acc[1] = fmaf(w1, bfloat_hi(u1.x), acc[1]);
            acc[2] = fmaf(w1, bfloat_lo(u1.y), acc[2]);
            acc[3] = fmaf(w1, bfloat_hi(u1.y), acc[3]);
        }
        for (; j < kmax; j += 4) {
            int e = j + q;
            int s = __shfl(ev.x, e);
            float w = __int_as_float(__shfl(ev.y, e));
            uint2 u = yU2[(size_t)s * 16 + s16];
            acc[0] = fmaf(w, bfloat_lo(u.x), acc[0]);
            acc[1] = fmaf(w, bfloat_hi(u.x), acc[1]);
            acc[2] = fmaf(w, bfloat_lo(u.y), acc[2]);
            acc[3] = fmaf(w, bfloat_hi(u.y), acc[3]);
        }
    }
    #pragma unroll
    for (int i = 0; i < 4; i++) {
        acc[i] += __shfl_xor(acc[i], 16);
        acc[i] += __shfl_xor(acc[i], 32);
    }
    if (lane < 16) {
        const int c = s16 * 4;
        float4 o;
        o.x = acc[0] + b_out[c + 0];
        o.y = acc[1] + b_out[c + 1];
        o.z = acc[2] + b_out[c + 2];
        o.w = acc[3] + b_out[c + 3];
        *(float4*)(out + (size_t)node * 64 + c) = o;
    }
}

// ---------------- input GEMM: z(bf16) = x @ W_in ----------------
__global__ __launch_bounds__(256) void k_gemm_in(
    const float* __restrict__ A, const float* __restrict__ W,
    unsigned int* __restrict__ zU)
{
    __shared__ float As[32][128];
    const int tid = threadIdx.x;
    const int row0 = blockIdx.x * 32;
    {
        const float4* srcp = (const float4*)(A + (size_t)row0 * 128);
        float4* dl = (float4*)(&As[0][0]);
        #pragma unroll
        for (int it = 0; it < 4; it++) {
            int idx = tid + it * 256;
            int r = idx >> 5;
            float4 v = make_float4(0.f, 0.f, 0.f, 0.f);
            if (row0 + r < N_NODES) v = srcp[idx];
            dl[idx] = v;
        }
    }
    __syncthreads();

    const int rg = tid >> 5;
    const int c0 = (tid & 31) * 4;
    float acc[4][4];
    #pragma unroll
    for (int i = 0; i < 4; i++)
        #pragma unroll
        for (int j = 0; j < 4; j++) acc[i][j] = 0.f;

    #pragma unroll 4
    for (int k = 0; k < 128; k++) {
        float a0 = As[rg * 4 + 0][k], a1 = As[rg * 4 + 1][k];
        float a2 = As[rg * 4 + 2][k], a3 = As[rg * 4 + 3][k];
        float4 wv = *(const float4*)(W + (size_t)k * 128 + c0);
        float w[4] = {wv.x, wv.y, wv.z, wv.w};
        #pragma unroll
        for (int j = 0; j < 4; j++) {
            acc[0][j] = fmaf(a0, w[j], acc[0][j]);
            acc[1][j] = fmaf(a1, w[j], acc[1][j]);
            acc[2][j] = fmaf(a2, w[j], acc[2][j]);
            acc[3][j] = fmaf(a3, w[j], acc[3][j]);
        }
    }

    #pragma unroll
    for (int i = 0; i < 4; i++) {
        int r = row0 + rg * 4 + i;
        if (r < N_NODES) {
            uint2 pk = make_uint2(pack2bf(acc[i][0], acc[i][1]), pack2bf(acc[i][2], acc[i][3]));
            *(uint2*)(zU + (size_t)r * 64 + (c0 >> 1)) = pk;
        }
    }
}

// ---------------- fused layer (32-row tile, 512 threads / 8 waves, 1563 blocks) ----------------
// h_out(bf16) = relu((1-beta)*t + beta*(t @ W)),  t = 0.5*spmm(h bf16) + 0.5*x0(bf16)
__global__ __launch_bounds__(512) void k_layer(
    const int* __restrict__ off, const int2* __restrict__ ep,
    const unsigned int* __restrict__ hU, const unsigned int* __restrict__ x0U,
    const float* __restrict__ W, unsigned int* __restrict__ hOutU, float beta)
{
    __shared__ float As[32][128];
    const int tid = threadIdx.x;
    const int wave = tid >> 6, lane = tid & 63;
    const int row0 = blockIdx.x * 32;
    const int wnode0 = row0 + wave * 4;          // 8 waves x 4 nodes = 32 rows
    const int c = lane * 2;

    // preload off[wnode0 .. wnode0+4] wave-parallel
    int offv = 0;
    if (lane < 5) {
        int nn = wnode0 + lane;
        if (nn > N_NODES) nn = N_NODES;
        offv = off[nn];
    }

    // phase 1: spmm -> t -> LDS (each wave: 4 nodes)
    #pragma unroll 1
    for (int i = 0; i < 4; i++) {
        const int node = wnode0 + i;
        float ax = 0.f, ay = 0.f;
        if (node < N_NODES) {
            const int lo = __shfl(offv, i), hi = __shfl(offv, i + 1);
            unsigned int xv = x0U[(size_t)node * 64 + lane];   // issue early; independent of gather
            gatherB2(ep, lo, hi, hU, lane, ax, ay);
            ax = 0.5f * ax + 0.5f * bfloat_lo(xv);
            ay = 0.5f * ay + 0.5f * bfloat_hi(xv);
        }
        *(float2*)(&As[wave * 4 + i][c]) = make_float2(ax, ay);
    }
    __syncthreads();

    // phase 2: gemm (32x128 tile, 512 threads -> acc[2][4]) + GCNII epilogue, h' written bf16
    const int rg = tid >> 5;          // 0..15 -> rows rg*2, rg*2+1
    const int c0 = (tid & 31) * 4;

    float acc[2][4];
    #pragma unroll
    for (int i = 0; i < 2; i++)
        #pragma unroll
        for (int j = 0; j < 4; j++) acc[i][j] = 0.f;

    #pragma unroll 4
    for (int k = 0; k < 128; k++) {
        float a0 = As[rg * 2 + 0][k];
        float a1 = As[rg * 2 + 1][k];
        float4 wv = *(const float4*)(W + (size_t)k * 128 + c0);
        float w[4] = {wv.x, wv.y, wv.z, wv.w};
        #pragma unroll
        for (int j = 0; j < 4; j++) {
            acc[0][j] = fmaf(a0, w[j], acc[0][j]);
            acc[1][j] = fmaf(a1, w[j], acc[1][j]);
        }
    }

    const float omb = 1.f - beta;
    #pragma unroll
    for (int i = 0; i < 2; i++) {
        int r = row0 + rg * 2 + i;
        if (r < N_NODES) {
            float v0 = fmaxf(omb * As[rg * 2 + i][c0 + 0] + beta * acc[i][0], 0.f);
            float v1 = fmaxf(omb * As[rg * 2 + i][c0 + 1] + beta * acc[i][1], 0.f);
            float v2 = fmaxf(omb * As[rg * 2 + i][c0 + 2] + beta * acc[i][2], 0.f);
            float v3 = fmaxf(omb * As[rg * 2 + i][c0 + 3] + beta * acc[i][3], 0.f);
            uint2 pk = make_uint2(pack2bf(v0, v1), pack2bf(v2, v3));
            *(uint2*)(hOutU + (size_t)r * 64 + (c0 >> 1)) = pk;
        }
    }
}

// ---------------- output GEMM: y(bf16) = h(bf16) @ W_out ----------------
__global__ __launch_bounds__(256) void k_gemm_out(
    const unsigned int* __restrict__ hU, const float* __restrict__ W,
    unsigned int* __restrict__ yU)
{
    __shared__ float As[32][128];
    const int tid = threadIdx.x;
    const int row0 = blockIdx.x * 32;
    {
        const uint4* srcp = (const uint4*)hU;   // row = 16 uint4 (8 ch each)
        #pragma unroll
        for (int it = 0; it < 2; it++) {
            int idx = tid + it * 256;           // 0..511
            int r = idx >> 4;
            int cc = (idx & 15) * 8;
            uint4 v = make_uint4(0u, 0u, 0u, 0u);
            if (row0 + r < N_NODES) v = srcp[(size_t)(row0 + r) * 16 + (idx & 15)];
            As[r][cc + 0] = bfloat_lo(v.x); As[r][cc + 1] = bfloat_hi(v.x);
            As[r][cc + 2] = bfloat_lo(v.y); As[r][cc + 3] = bfloat_hi(v.y);
            As[r][cc + 4] = bfloat_lo(v.z); As[r][cc + 5] = bfloat_hi(v.z);
            As[r][cc + 6] = bfloat_lo(v.w); As[r][cc + 7] = bfloat_hi(v.w);
        }
    }
    __syncthreads();

    const int rg = tid >> 5;
    const int c0 = (tid & 31) * 2;
    float acc[4][2];
    #pragma unroll
    for (int i = 0; i < 4; i++) { acc[i][0] = 0.f; acc[i][1] = 0.f; }

    #pragma unroll 4
    for (int k = 0; k < 128; k++) {
        float a0 = As[rg * 4 + 0][k], a1 = As[rg * 4 + 1][k];
        float a2 = As[rg * 4 + 2][k], a3 = As[rg * 4 + 3][k];
        float2 wv = *(const float2*)(W + (size_t)k * OUTC + c0);
        acc[0][0] = fmaf(a0, wv.x, acc[0][0]); acc[0][1] = fmaf(a0, wv.y, acc[0][1]);
        acc[1][0] = fmaf(a1, wv.x, acc[1][0]); acc[1][1] = fmaf(a1, wv.y, acc[1][1]);
        acc[2][0] = fmaf(a2, wv.x, acc[2][0]); acc[2][1] = fmaf(a2, wv.y, acc[2][1]);
        acc[3][0] = fmaf(a3, wv.x, acc[3][0]); acc[3][1] = fmaf(a3, wv.y, acc[3][1]);
    }

    #pragma unroll
    for (int i = 0; i < 4; i++) {
        int r = row0 + rg * 4 + i;
        if (r < N_NODES) {
            yU[(size_t)r * 32 + (c0 >> 1)] = pack2bf(acc[i][0], acc[i][1]);
        }
    }
}

// ---------------- launch ----------------

extern "C" void kernel_launch(void* const* d_in, const int* in_sizes, int n_in,
                              void* d_out, int out_size, void* d_ws, size_t ws_size,
                              hipStream_t stream)
{
    const float* x     = (const float*)d_in[0];
    const int*   ei    = (const int*)d_in[1];
    const float* ew    = (const float*)d_in[2];
    const float* W_in  = (const float*)d_in[3];
    const float* b_in  = (const float*)d_in[4];
    const float* W_lay = (const float*)d_in[5];
    const float* W_out = (const float*)d_in[6];
    const float* b_out = (const float*)d_in[7];
    float* out = (float*)d_out;

    const int* src = ei;
    const int* dst = ei + N_EDGES;

    char* p = (char*)d_ws;
    auto alloc = [&](size_t bytes) -> char* {
        char* q = p;
        p += (bytes + 255) & ~(size_t)255;
        return q;
    };
    int*          cursor = (int*)alloc((size_t)N_NODES * 4);
    int*          off    = (int*)alloc((size_t)(N_NODES + 1) * 4);
    int2*         ep     = (int2*)alloc((size_t)N_EDGES * 8);
    int*          bsum   = (int*)alloc((size_t)SCAN_B * 4);
    unsigned int* zU     = (unsigned int*)alloc((size_t)N_NODES * 64 * 4); // z bf16 [N][128]
    unsigned int* x0U    = (unsigned int*)alloc((size_t)N_NODES * 64 * 4); // x0 bf16
    unsigned int* hA     = (unsigned int*)alloc((size_t)N_NODES * 64 * 4); // h bf16
    unsigned int* hB     = (unsigned int*)alloc((size_t)N_NODES * 64 * 4);
    unsigned int* yB     = (unsigned int*)alloc((size_t)N_NODES * 32 * 4); // y bf16 [N][64]

    // CSR build
    k_zero<<<(N_NODES + 255) / 256, 256, 0, stream>>>(cursor, N_NODES);
    k_count<<<(N_EDGES + 255) / 256, 256, 0, stream>>>(dst, cursor, N_EDGES);
    k_scanA<<<SCAN_B, SCAN_T, 0, stream>>>(cursor, bsum);
    k_scanB<<<SCAN_B, SCAN_T, 0, stream>>>(cursor, off, bsum);
    k_scatter<<<(N_EDGES + 255) / 256, 256, 0, stream>>>(src, dst, ew, cursor, ep, N_EDGES);

    const int gemmGrid  = (N_NODES + 31) / 32;   // 1563
    const int spmmGrid  = (N_NODES + 3) / 4;     // 12500 (exact)

    // z = x @ W_in -> zU (bf16)
    k_gemm_in<<<gemmGrid, 256, 0, stream>>>(x, W_in, zU);
    // h0 = relu(spmm(z) + b_in) -> hA (bf16), x0U (bf16)
    k_spmm_in<<<spmmGrid, 256, 0, stream>>>(off, ep, zU, b_in, hA, x0U);

    unsigned int* hin = hA;
    unsigned int* hout = hB;
    for (int l = 0; l < NLAYERS; l++) {
        float beta = logf(1.0f / (float)(l + 1) + 1.0f);
        k_layer<<<gemmGrid, 512, 0, stream>>>(off, ep, hin, x0U,
                                              W_lay + (size_t)l * HID * HID, hout, beta);
        unsigned int* tmp = hin; hin = hout; hout = tmp;
    }

    // y = h @ W_out -> yB (bf16)
    k_gemm_out<<<gemmGrid, 256, 0, stream>>>(hin, W_out, yB);
    // out = spmm(y) + b_out
    k_spmm_out<<<spmmGrid, 256, 0, stream>>>(off, ep, (const uint2*)yB, b_out, out);
}

// Round 12
// 714.934 us; speedup vs baseline: 1.2904x; 1.2904x over previous
//
#include <hip/hip_runtime.h>
#include <math.h>

#define N_NODES 50000
#define N_EDGES 800000
#define HID 128
#define OUTC 64
#define NLAYERS 8

#define SCAN_B 64
#define SCAN_T 256
#define SCAN_C 4   // 64*256*4 = 65536 >= 50000

// ---------------- bf16 helpers (manual, RNE) ----------------

__device__ __forceinline__ float bfloat_lo(unsigned int u) {
    return __int_as_float((int)(u << 16));
}
__device__ __forceinline__ float bfloat_hi(unsigned int u) {
    return __int_as_float((int)(u & 0xFFFF0000u));
}
__device__ __forceinline__ unsigned int f2bf(float f) {
    unsigned int u = (unsigned int)__float_as_int(f);
    return (u + 0x7FFFu + ((u >> 16) & 1u)) >> 16;
}
__device__ __forceinline__ unsigned int pack2bf(float a, float b) {
    return f2bf(a) | (f2bf(b) << 16);
}

// ---------------- CSR build ----------------

__global__ void k_zero(int* __restrict__ p, int n) {
    int i = blockIdx.x * blockDim.x + threadIdx.x;
    if (i < n) p[i] = 0;
}

__global__ void k_count(const int* __restrict__ dst, int* __restrict__ deg, int E) {
    int e = blockIdx.x * blockDim.x + threadIdx.x;
    if (e < E) atomicAdd(&deg[dst[e]], 1);
}

__global__ __launch_bounds__(SCAN_T) void k_scanA(const int* __restrict__ deg, int* __restrict__ bsum) {
    __shared__ int red[SCAN_T];
    const int t = threadIdx.x, b = blockIdx.x;
    const int g = b * SCAN_T + t;
    int lo = g * SCAN_C; if (lo > N_NODES) lo = N_NODES;
    int hi = lo + SCAN_C; if (hi > N_NODES) hi = N_NODES;
    int s = 0;
    for (int i = lo; i < hi; i++) s += deg[i];
    red[t] = s;
    __syncthreads();
    for (int d = SCAN_T / 2; d > 0; d >>= 1) {
        if (t < d) red[t] += red[t + d];
        __syncthreads();
    }
    if (t == 0) bsum[b] = red[0];
}

__global__ __launch_bounds__(SCAN_T) void k_scanB(int* __restrict__ cur, int* __restrict__ off,
                                                  const int* __restrict__ bsum) {
    __shared__ int pre[SCAN_T];
    __shared__ int baseSh;
    const int t = threadIdx.x, b = blockIdx.x;
    const int g = b * SCAN_T + t;
    int lo = g * SCAN_C; if (lo > N_NODES) lo = N_NODES;
    int hi = lo + SCAN_C; if (hi > N_NODES) hi = N_NODES;
    int s = 0;
    for (int i = lo; i < hi; i++) s += cur[i];
    pre[t] = s;
    if (t == 0) {
        int acc = 0;
        for (int j = 0; j < b; j++) acc += bsum[j];
        baseSh = acc;
    }
    __syncthreads();
    for (int d = 1; d < SCAN_T; d <<= 1) {
        int v = (t >= d) ? pre[t - d] : 0;
        __syncthreads();
        pre[t] += v;
        __syncthreads();
    }
    int running = baseSh + pre[t] - s;
    for (int i = lo; i < hi; i++) {
        int d = cur[i];
        off[i] = running;
        cur[i] = running;
        running += d;
        if (i == N_NODES - 1) off[N_NODES] = running;
    }
}

__global__ void k_scatter(const int* __restrict__ src, const int* __restrict__ dst,
                          const float* __restrict__ w, int* __restrict__ cursor,
                          int2* __restrict__ ep, int E) {
    int e = blockIdx.x * blockDim.x + threadIdx.x;
    if (e < E) {
        int d = dst[e];
        int pos = atomicAdd(&cursor[d], 1);
        ep[pos] = make_int2(src[e], __float_as_int(w[e]));
    }
}

// ---------------- bf16 gather (128 ch): one edge per wave-instruction ----------------
__device__ __forceinline__ void gatherB2(const int2* __restrict__ ep, int lo, int hi,
                                         const unsigned int* __restrict__ featsU, int lane,
                                         float& ax, float& ay)
{
    for (int base = lo; base < hi; base += 64) {
        const int cnt = min(hi - base, 64);
        int2 ev = make_int2(0, 0);
        if (lane < cnt) ev = ep[base + lane];
        int j = 0;
        for (; j + 8 <= cnt; j += 8) {
            int s0 = __shfl(ev.x, j + 0), s1 = __shfl(ev.x, j + 1);
            int s2 = __shfl(ev.x, j + 2), s3 = __shfl(ev.x, j + 3);
            int s4 = __shfl(ev.x, j + 4), s5 = __shfl(ev.x, j + 5);
            int s6 = __shfl(ev.x, j + 6), s7 = __shfl(ev.x, j + 7);
            float w0 = __int_as_float(__shfl(ev.y, j + 0));
            float w1 = __int_as_float(__shfl(ev.y, j + 1));
            float w2 = __int_as_float(__shfl(ev.y, j + 2));
            float w3 = __int_as_float(__shfl(ev.y, j + 3));
            float w4 = __int_as_float(__shfl(ev.y, j + 4));
            float w5 = __int_as_float(__shfl(ev.y, j + 5));
            float w6 = __int_as_float(__shfl(ev.y, j + 6));
            float w7 = __int_as_float(__shfl(ev.y, j + 7));
            unsigned int u0 = featsU[(size_t)s0 * 64 + lane];
            unsigned int u1 = featsU[(size_t)s1 * 64 + lane];
            unsigned int u2 = featsU[(size_t)s2 * 64 + lane];
            unsigned int u3 = featsU[(size_t)s3 * 64 + lane];
            unsigned int u4 = featsU[(size_t)s4 * 64 + lane];
            unsigned int u5 = featsU[(size_t)s5 * 64 + lane];
            unsigned int u6 = featsU[(size_t)s6 * 64 + lane];
            unsigned int u7 = featsU[(size_t)s7 * 64 + lane];
            ax = fmaf(w0, bfloat_lo(u0), ax); ay = fmaf(w0, bfloat_hi(u0), ay);
            ax = fmaf(w1, bfloat_lo(u1), ax); ay = fmaf(w1, bfloat_hi(u1), ay);
            ax = fmaf(w2, bfloat_lo(u2), ax); ay = fmaf(w2, bfloat_hi(u2), ay);
            ax = fmaf(w3, bfloat_lo(u3), ax); ay = fmaf(w3, bfloat_hi(u3), ay);
            ax = fmaf(w4, bfloat_lo(u4), ax); ay = fmaf(w4, bfloat_hi(u4), ay);
            ax = fmaf(w5, bfloat_lo(u5), ax); ay = fmaf(w5, bfloat_hi(u5), ay);
            ax = fmaf(w6, bfloat_lo(u6), ax); ay = fmaf(w6, bfloat_hi(u6), ay);
            ax = fmaf(w7, bfloat_lo(u7), ax); ay = fmaf(w7, bfloat_hi(u7), ay);
        }
        for (; j < cnt; j++) {
            int s = __shfl(ev.x, j);
            float w = __int_as_float(__shfl(ev.y, j));
            unsigned int u = featsU[(size_t)s * 64 + lane];
            ax = fmaf(w, bfloat_lo(u), ax); ay = fmaf(w, bfloat_hi(u), ay);
        }
    }
}

// ---------------- input spmm: h0 = relu(spmm(z bf16) + b_in) -> h bf16 AND x0 bf16 ----------------
__global__ __launch_bounds__(256) void k_spmm_in(
    const int* __restrict__ off, const int2* __restrict__ ep,
    const unsigned int* __restrict__ zU, const float* __restrict__ b_in,
    unsigned int* __restrict__ hU, unsigned int* __restrict__ x0U)
{
    const int wave = threadIdx.x >> 6;
    const int lane = threadIdx.x & 63;
    const int node = blockIdx.x * 4 + wave;
    if (node >= N_NODES) return;
    const int lo = off[node], hi = off[node + 1];

    float ax = 0.f, ay = 0.f;
    gatherB2(ep, lo, hi, zU, lane, ax, ay);
    const int c = lane * 2;
    float r0 = fmaxf(ax + b_in[c], 0.f);
    float r1 = fmaxf(ay + b_in[c + 1], 0.f);
    unsigned int pk = pack2bf(r0, r1);
    hU [(size_t)node * 64 + lane] = pk;
    x0U[(size_t)node * 64 + lane] = pk;
}

// ---------------- final spmm: out = spmm(y bf16, 64ch) + b_out (4 edges per load) ----------------
__global__ __launch_bounds__(256) void k_spmm_out(
    const int* __restrict__ off, const int2* __restrict__ ep,
    const uint2* __restrict__ yU2, const float* __restrict__ b_out,
    float* __restrict__ out)
{
    const int wave = threadIdx.x >> 6;
    const int lane = threadIdx.x & 63;
    const int node = blockIdx.x * 4 + wave;
    if (node >= N_NODES) return;
    const int q = lane >> 4;       // edge slot within quad
    const int s16 = lane & 15;     // ch group: ch = s16*4..+3

    float acc[4] = {0.f, 0.f, 0.f, 0.f};
    const int lo = off[node], hi = off[node + 1];
    for (int base = lo; base < hi; base += 64) {
        const int cnt = min(hi - base, 64);
        int2 ev = make_int2(0, 0);
        if (lane < cnt) ev = ep[base + lane];
        const int kmax = (cnt + 3) & ~3;
        int j = 0;
        for (; j + 8 <= kmax; j += 8) {
            int e0 = j + q, e1 = j + 4 + q;
            int s0 = __shfl(ev.x, e0), s1 = __shfl(ev.x, e1);
            float w0 = __int_as_float(__shfl(ev.y, e0));
            float w1 = __int_as_float(__shfl(ev.y, e1));
            uint2 u0 = yU2[(size_t)s0 * 16 + s16];
            uint2 u1 = yU2[(size_t)s1 * 16 + s16];
            acc[0] = fmaf(w0, bfloat_lo(u0.x), acc[0]);
            acc[1] = fmaf(w0, bfloat_hi(u0.x), acc[1]);
            acc[2] = fmaf(w0, bfloat_lo(u0.y), acc[2]);
            acc[3] = fmaf(w0, bfloat_hi(u0.y), acc[3]);
            acc[0] = fmaf(w1, bfloat_lo(u1.x), acc[0]);
            acc[1] = fmaf(w1, bfloat_hi(u1.x), acc[1]);
            acc[2] = fmaf(w1, bfloat_lo(u1.y), acc[2]);
            acc[3] = fmaf(w1, bfloat_hi(u1.y), acc[3]);
        }
        for (; j < kmax; j += 4) {
            int e = j + q;
            int s = __shfl(ev.x, e);
            float w = __int_as_float(__shfl(ev.y, e));
            uint2 u = yU2[(size_t)s * 16 + s16];
            acc[0] = fmaf(w, bfloat_lo(u.x), acc[0]);
            acc[1] = fmaf(w, bfloat_hi(u.x), acc[1]);
            acc[2] = fmaf(w, bfloat_lo(u.y), acc[2]);
            acc[3] = fmaf(w, bfloat_hi(u.y), acc[3]);
        }
    }
    #pragma unroll
    for (int i = 0; i < 4; i++) {
        acc[i] += __shfl_xor(acc[i], 16);
        acc[i] += __shfl_xor(acc[i], 32);
    }
    if (lane < 16) {
        const int c = s16 * 4;
        float4 o;
        o.x = acc[0] + b_out[c + 0];
        o.y = acc[1] + b_out[c + 1];
        o.z = acc[2] + b_out[c + 2];
        o.w = acc[3] + b_out[c + 3];
        *(float4*)(out + (size_t)node * 64 + c) = o;
    }
}

// ---------------- input GEMM: z(bf16) = x @ W_in ----------------
__global__ __launch_bounds__(256) void k_gemm_in(
    const float* __restrict__ A, const float* __restrict__ W,
    unsigned int* __restrict__ zU)
{
    __shared__ float As[32][128];
    const int tid = threadIdx.x;
    const int row0 = blockIdx.x * 32;
    {
        const float4* srcp = (const float4*)(A + (size_t)row0 * 128);
        float4* dl = (float4*)(&As[0][0]);
        #pragma unroll
        for (int it = 0; it < 4; it++) {
            int idx = tid + it * 256;
            int r = idx >> 5;
            float4 v = make_float4(0.f, 0.f, 0.f, 0.f);
            if (row0 + r < N_NODES) v = srcp[idx];
            dl[idx] = v;
        }
    }
    __syncthreads();

    const int rg = tid >> 5;
    const int c0 = (tid & 31) * 4;
    float acc[4][4];
    #pragma unroll
    for (int i = 0; i < 4; i++)
        #pragma unroll
        for (int j = 0; j < 4; j++) acc[i][j] = 0.f;

    #pragma unroll 4
    for (int k = 0; k < 128; k++) {
        float a0 = As[rg * 4 + 0][k], a1 = As[rg * 4 + 1][k];
        float a2 = As[rg * 4 + 2][k], a3 = As[rg * 4 + 3][k];
        float4 wv = *(const float4*)(W + (size_t)k * 128 + c0);
        float w[4] = {wv.x, wv.y, wv.z, wv.w};
        #pragma unroll
        for (int j = 0; j < 4; j++) {
            acc[0][j] = fmaf(a0, w[j], acc[0][j]);
            acc[1][j] = fmaf(a1, w[j], acc[1][j]);
            acc[2][j] = fmaf(a2, w[j], acc[2][j]);
            acc[3][j] = fmaf(a3, w[j], acc[3][j]);
        }
    }

    #pragma unroll
    for (int i = 0; i < 4; i++) {
        int r = row0 + rg * 4 + i;
        if (r < N_NODES) {
            uint2 pk = make_uint2(pack2bf(acc[i][0], acc[i][1]), pack2bf(acc[i][2], acc[i][3]));
            *(uint2*)(zU + (size_t)r * 64 + (c0 >> 1)) = pk;
        }
    }
}

// ---------------- fused layer (R9 structure + paired-chain gather + ep prefetch) ----------------
// 256 threads, 4 waves x 8 nodes, 32-row tile, 1563 blocks.
// h_out(bf16) = relu((1-beta)*t + beta*(t @ W)),  t = 0.5*spmm(h bf16) + 0.5*x0(bf16)
__global__ __launch_bounds__(256) void k_layer(
    const int* __restrict__ off, const int2* __restrict__ ep,
    const unsigned int* __restrict__ hU, const unsigned int* __restrict__ x0U,
    const float* __restrict__ W, unsigned int* __restrict__ hOutU, float beta)
{
    __shared__ float As[32][128];
    const int tid = threadIdx.x;
    const int wave = tid >> 6, lane = tid & 63;
    const int row0 = blockIdx.x * 32;
    const int wnode0 = row0 + wave * 8;
    const int c = lane * 2;

    // preload off[wnode0 .. wnode0+8] wave-parallel
    int offv = 0;
    if (lane < 9) {
        int nn = wnode0 + lane;
        if (nn > N_NODES) nn = N_NODES;
        offv = off[nn];
    }

    // prefetch pair 0 edge segments (zero-pad: s=0,w=0 lanes are harmless)
    int loA = __shfl(offv, 0), hiA = __shfl(offv, 1), hiB = __shfl(offv, 2);
    int2 evA = make_int2(0, 0), evB = make_int2(0, 0);
    if (lane < min(hiA - loA, 64)) evA = ep[loA + lane];
    if (lane < min(hiB - hiA, 64)) evB = ep[hiA + lane];

    // phase 1: spmm -> t -> LDS; 4 pairs of nodes, 2 independent chains, 16 loads in flight
    #pragma unroll 1
    for (int p = 0; p < 4; p++) {
        const int nodeA = wnode0 + 2 * p, nodeB = nodeA + 1;
        const int dA = hiA - loA, dB = hiB - hiA;
        const int loB = hiA;
        const bool vA = nodeA < N_NODES, vB = nodeB < N_NODES;

        // prefetch next pair's edge segments (hides ep latency under this pair's gather)
        int nloA = 0, nhiA = 0, nhiB = 0;
        int2 nevA = make_int2(0, 0), nevB = make_int2(0, 0);
        if (p < 3) {
            nloA = __shfl(offv, 2 * p + 2);
            nhiA = __shfl(offv, 2 * p + 3);
            nhiB = __shfl(offv, 2 * p + 4);
            if (lane < min(nhiA - nloA, 64)) nevA = ep[nloA + lane];
            if (lane < min(nhiB - nhiA, 64)) nevB = ep[nhiA + lane];
        }

        // x0 issued early (independent of gather)
        unsigned int xvA = 0, xvB = 0;
        if (vA) xvA = x0U[(size_t)nodeA * 64 + lane];
        if (vB) xvB = x0U[(size_t)nodeB * 64 + lane];

        float axA = 0.f, ayA = 0.f, axB = 0.f, ayB = 0.f;
        if (dA <= 64 && dB <= 64) {
            const int kmax = max(dA, dB);          // zero-padded: run both chains to kmax
            for (int j = 0; j < kmax; j += 8) {
                int a0 = __shfl(evA.x, j + 0), a1 = __shfl(evA.x, j + 1);
                int a2 = __shfl(evA.x, j + 2), a3 = __shfl(evA.x, j + 3);
                int a4 = __shfl(evA.x, j + 4), a5 = __shfl(evA.x, j + 5);
                int a6 = __shfl(evA.x, j + 6), a7 = __shfl(evA.x, j + 7);
                int b0 = __shfl(evB.x, j + 0), b1 = __shfl(evB.x, j + 1);
                int b2 = __shfl(evB.x, j + 2), b3 = __shfl(evB.x, j + 3);
                int b4 = __shfl(evB.x, j + 4), b5 = __shfl(evB.x, j + 5);
                int b6 = __shfl(evB.x, j + 6), b7 = __shfl(evB.x, j + 7);
                unsigned int uA0 = hU[(size_t)a0 * 64 + lane];
                unsigned int uA1 = hU[(size_t)a1 * 64 + lane];
                unsigned int uA2 = hU[(size_t)a2 * 64 + lane];
                unsigned int uA3 = hU[(size_t)a3 * 64 + lane];
                unsigned int uA4 = hU[(size_t)a4 * 64 + lane];
                unsigned int uA5 = hU[(size_t)a5 * 64 + lane];
                unsigned int uA6 = hU[(size_t)a6 * 64 + lane];
                unsigned int uA7 = hU[(size_t)a7 * 64 + lane];
                unsigned int uB0 = hU[(size_t)b0 * 64 + lane];
                unsigned int uB1 = hU[(size_t)b1 * 64 + lane];
                unsigned int uB2 = hU[(size_t)b2 * 64 + lane];
                unsigned int uB3 = hU[(size_t)b3 * 64 + lane];
                unsigned int uB4 = hU[(size_t)b4 * 64 + lane];
                unsigned int uB5 = hU[(size_t)b5 * 64 + lane];
                unsigned int uB6 = hU[(size_t)b6 * 64 + lane];
                unsigned int uB7 = hU[(size_t)b7 * 64 + lane];
                float wA0 = __int_as_float(__shfl(evA.y, j + 0));
                float wA1 = __int_as_float(__shfl(evA.y, j + 1));
                float wA2 = __int_as_float(__shfl(evA.y, j + 2));
                float wA3 = __int_as_float(__shfl(evA.y, j + 3));
                float wA4 = __int_as_float(__shfl(evA.y, j + 4));
                float wA5 = __int_as_float(__shfl(evA.y, j + 5));
                float wA6 = __int_as_float(__shfl(evA.y, j + 6));
                float wA7 = __int_as_float(__shfl(evA.y, j + 7));
                float wB0 = __int_as_float(__shfl(evB.y, j + 0));
                float wB1 = __int_as_float(__shfl(evB.y, j + 1));
                float wB2 = __int_as_float(__shfl(evB.y, j + 2));
                float wB3 = __int_as_float(__shfl(evB.y, j + 3));
                float wB4 = __int_as_float(__shfl(evB.y, j + 4));
                float wB5 = __int_as_float(__shfl(evB.y, j + 5));
                float wB6 = __int_as_float(__shfl(evB.y, j + 6));
                float wB7 = __int_as_float(__shfl(evB.y, j + 7));
                axA = fmaf(wA0, bfloat_lo(uA0), axA); ayA = fmaf(wA0, bfloat_hi(uA0), ayA);
                axB = fmaf(wB0, bfloat_lo(uB0), axB); ayB = fmaf(wB0, bfloat_hi(uB0), ayB);
                axA = fmaf(wA1, bfloat_lo(uA1), axA); ayA = fmaf(wA1, bfloat_hi(uA1), ayA);
                axB = fmaf(wB1, bfloat_lo(uB1), axB); ayB = fmaf(wB1, bfloat_hi(uB1), ayB);
                axA = fmaf(wA2, bfloat_lo(uA2), axA); ayA = fmaf(wA2, bfloat_hi(uA2), ayA);
                axB = fmaf(wB2, bfloat_lo(uB2), axB); ayB = fmaf(wB2, bfloat_hi(uB2), ayB);
                axA = fmaf(wA3, bfloat_lo(uA3), axA); ayA = fmaf(wA3, bfloat_hi(uA3), ayA);
                axB = fmaf(wB3, bfloat_lo(uB3), axB); ayB = fmaf(wB3, bfloat_hi(uB3), ayB);
                axA = fmaf(wA4, bfloat_lo(uA4), axA); ayA = fmaf(wA4, bfloat_hi(uA4), ayA);
                axB = fmaf(wB4, bfloat_lo(uB4), axB); ayB = fmaf(wB4, bfloat_hi(uB4), ayB);
                axA = fmaf(wA5, bfloat_lo(uA5), axA); ayA = fmaf(wA5, bfloat_hi(uA5), ayA);
                axB = fmaf(wB5, bfloat_lo(uB5), axB); ayB = fmaf(wB5, bfloat_hi(uB5), ayB);
                axA = fmaf(wA6, bfloat_lo(uA6), axA); ayA = fmaf(wA6, bfloat_hi(uA6), ayA);
                axB = fmaf(wB6, bfloat_lo(uB6), axB); ayB = fmaf(wB6, bfloat_hi(uB6), ayB);
                axA = fmaf(wA7, bfloat_lo(uA7), axA); ayA = fmaf(wA7, bfloat_hi(uA7), ayA);
                axB = fmaf(wB7, bfloat_lo(uB7), axB); ayB = fmaf(wB7, bfloat_hi(uB7), ayB);
            }
        } else {
            // rare fallback (degree > 64)
            gatherB2(ep, loA, hiA, hU, lane, axA, ayA);
            gatherB2(ep, loB, hiB, hU, lane, axB, ayB);
        }

        if (vA) {
            axA = 0.5f * axA + 0.5f * bfloat_lo(xvA);
            ayA = 0.5f * ayA + 0.5f * bfloat_hi(xvA);
        } else { axA = 0.f; ayA = 0.f; }
        if (vB) {
            axB = 0.5f * axB + 0.5f * bfloat_lo(xvB);
            ayB = 0.5f * ayB + 0.5f * bfloat_hi(xvB);
        } else { axB = 0.f; ayB = 0.f; }
        *(float2*)(&As[wave * 8 + 2 * p + 0][c]) = make_float2(axA, ayA);
        *(float2*)(&As[wave * 8 + 2 * p + 1][c]) = make_float2(axB, ayB);

        loA = nloA; hiA = nhiA; hiB = nhiB; evA = nevA; evB = nevB;
    }
    __syncthreads();

    // phase 2: gemm (32x128 tile, 256 threads, acc[4][4]) + GCNII epilogue, h' written bf16
    const int rg = tid >> 5;          // rows rg*4 .. rg*4+3
    const int c0 = (tid & 31) * 4;

    float acc[4][4];
    #pragma unroll
    for (int i = 0; i < 4; i++)
        #pragma unroll
        for (int j = 0; j < 4; j++) acc[i][j] = 0.f;

    #pragma unroll 4
    for (int k = 0; k < 128; k++) {
        float a0 = As[rg * 4 + 0][k], a1 = As[rg * 4 + 1][k];
        float a2 = As[rg * 4 + 2][k], a3 = As[rg * 4 + 3][k];
        float4 wv = *(const float4*)(W + (size_t)k * 128 + c0);
        float w[4] = {wv.x, wv.y, wv.z, wv.w};
        #pragma unroll
        for (int j = 0; j < 4; j++) {
            acc[0][j] = fmaf(a0, w[j], acc[0][j]);
            acc[1][j] = fmaf(a1, w[j], acc[1][j]);
            acc[2][j] = fmaf(a2, w[j], acc[2][j]);
            acc[3][j] = fmaf(a3, w[j], acc[3][j]);
        }
    }

    const float omb = 1.f - beta;
    #pragma unroll
    for (int i = 0; i < 4; i++) {
        int r = row0 + rg * 4 + i;
        if (r < N_NODES) {
            float v0 = fmaxf(omb * As[rg * 4 + i][c0 + 0] + beta * acc[i][0], 0.f);
            float v1 = fmaxf(omb * As[rg * 4 + i][c0 + 1] + beta * acc[i][1], 0.f);
            float v2 = fmaxf(omb * As[rg * 4 + i][c0 + 2] + beta * acc[i][2], 0.f);
            float v3 = fmaxf(omb * As[rg * 4 + i][c0 + 3] + beta * acc[i][3], 0.f);
            uint2 pk = make_uint2(pack2bf(v0, v1), pack2bf(v2, v3));
            *(uint2*)(hOutU + (size_t)r * 64 + (c0 >> 1)) = pk;
        }
    }
}

// ---------------- output GEMM: y(bf16) = h(bf16) @ W_out ----------------
__global__ __launch_bounds__(256) void k_gemm_out(
    const unsigned int* __restrict__ hU, const float* __restrict__ W,
    unsigned int* __restrict__ yU)
{
    __shared__ float As[32][128];
    const int tid = threadIdx.x;
    const int row0 = blockIdx.x * 32;
    {
        const uint4* srcp = (const uint4*)hU;   // row = 16 uint4 (8 ch each)
        #pragma unroll
        for (int it = 0; it < 2; it++) {
            int idx = tid + it * 256;           // 0..511
            int r = idx >> 4;
            int cc = (idx & 15) * 8;
            uint4 v = make_uint4(0u, 0u, 0u, 0u);
            if (row0 + r < N_NODES) v = srcp[(size_t)(row0 + r) * 16 + (idx & 15)];
            As[r][cc + 0] = bfloat_lo(v.x); As[r][cc + 1] = bfloat_hi(v.x);
            As[r][cc + 2] = bfloat_lo(v.y); As[r][cc + 3] = bfloat_hi(v.y);
            As[r][cc + 4] = bfloat_lo(v.z); As[r][cc + 5] = bfloat_hi(v.z);
            As[r][cc + 6] = bfloat_lo(v.w); As[r][cc + 7] = bfloat_hi(v.w);
        }
    }
    __syncthreads();

    const int rg = tid >> 5;
    const int c0 = (tid & 31) * 2;
    float acc[4][2];
    #pragma unroll
    for (int i = 0; i < 4; i++) { acc[i][0] = 0.f; acc[i][1] = 0.f; }

    #pragma unroll 4
    for (int k = 0; k < 128; k++) {
        float a0 = As[rg * 4 + 0][k], a1 = As[rg * 4 + 1][k];
        float a2 = As[rg * 4 + 2][k], a3 = As[rg * 4 + 3][k];
        float2 wv = *(const float2*)(W + (size_t)k * OUTC + c0);
        acc[0][0] = fmaf(a0, wv.x, acc[0][0]); acc[0][1] = fmaf(a0, wv.y, acc[0][1]);
        acc[1][0] = fmaf(a1, wv.x, acc[1][0]); acc[1][1] = fmaf(a1, wv.y, acc[1][1]);
        acc[2][0] = fmaf(a2, wv.x, acc[2][0]); acc[2][1] = fmaf(a2, wv.y, acc[2][1]);
        acc[3][0] = fmaf(a3, wv.x, acc[3][0]); acc[3][1] = fmaf(a3, wv.y, acc[3][1]);
    }

    #pragma unroll
    for (int i = 0; i < 4; i++) {
        int r = row0 + rg * 4 + i;
        if (r < N_NODES) {
            yU[(size_t)r * 32 + (c0 >> 1)] = pack2bf(acc[i][0], acc[i][1]);
        }
    }
}

// ---------------- launch ----------------

extern "C" void kernel_launch(void* const* d_in, const int* in_sizes, int n_in,
                              void* d_out, int out_size, void* d_ws, size_t ws_size,
                              hipStream_t stream)
{
    const float* x     = (const float*)d_in[0];
    const int*   ei    = (const int*)d_in[1];
    const float* ew    = (const float*)d_in[2];
    const float* W_in  = (const float*)d_in[3];
    const float* b_in  = (const float*)d_in[4];
    const float* W_lay = (const float*)d_in[5];
    const float* W_out = (const float*)d_in[6];
    const float* b_out = (const float*)d_in[7];
    float* out = (float*)d_out;

    const int* src = ei;
    const int* dst = ei + N_EDGES;

    char* p = (char*)d_ws;
    auto alloc = [&](size_t bytes) -> char* {
        char* q = p;
        p += (bytes + 255) & ~(size_t)255;
        return q;
    };
    int*          cursor = (int*)alloc((size_t)N_NODES * 4);
    int*          off    = (int*)alloc((size_t)(N_NODES + 1) * 4);
    int2*         ep     = (int2*)alloc((size_t)N_EDGES * 8);
    int*          bsum   = (int*)alloc((size_t)SCAN_B * 4);
    unsigned int* zU     = (unsigned int*)alloc((size_t)N_NODES * 64 * 4); // z bf16 [N][128]
    unsigned int* x0U    = (unsigned int*)alloc((size_t)N_NODES * 64 * 4); // x0 bf16
    unsigned int* hA     = (unsigned int*)alloc((size_t)N_NODES * 64 * 4); // h bf16
    unsigned int* hB     = (unsigned int*)alloc((size_t)N_NODES * 64 * 4);
    unsigned int* yB     = (unsigned int*)alloc((size_t)N_NODES * 32 * 4); // y bf16 [N][64]

    // CSR build
    k_zero<<<(N_NODES + 255) / 256, 256, 0, stream>>>(cursor, N_NODES);
    k_count<<<(N_EDGES + 255) / 256, 256, 0, stream>>>(dst, cursor, N_EDGES);
    k_scanA<<<SCAN_B, SCAN_T, 0, stream>>>(cursor, bsum);
    k_scanB<<<SCAN_B, SCAN_T, 0, stream>>>(cursor, off, bsum);
    k_scatter<<<(N_EDGES + 255) / 256, 256, 0, stream>>>(src, dst, ew, cursor, ep, N_EDGES);

    const int gemmGrid  = (N_NODES + 31) / 32;   // 1563
    const int spmmGrid  = (N_NODES + 3) / 4;     // 12500 (exact)

    // z = x @ W_in -> zU (bf16)
    k_gemm_in<<<gemmGrid, 256, 0, stream>>>(x, W_in, zU);
    // h0 = relu(spmm(z) + b_in) -> hA (bf16), x0U (bf16)
    k_spmm_in<<<spmmGrid, 256, 0, stream>>>(off, ep, zU, b_in, hA, x0U);

    unsigned int* hin = hA;
    unsigned int* hout = hB;
    for (int l = 0; l < NLAYERS; l++) {
        float beta = logf(1.0f / (float)(l + 1) + 1.0f);
        k_layer<<<gemmGrid, 256, 0, stream>>>(off, ep, hin, x0U,
                                              W_lay + (size_t)l * HID * HID, hout, beta);
        unsigned int* tmp = hin; hin = hout; hout = tmp;
    }

    // y = h @ W_out -> yB (bf16)
    k_gemm_out<<<gemmGrid, 256, 0, stream>>>(hin, W_out, yB);
    // out = spmm(y) + b_out
    k_spmm_out<<<spmmGrid, 256, 0, stream>>>(off, ep, (const uint2*)yB, b_out, out);
}